// Round 9
// baseline (281.975 us; speedup 1.0000x reference)
//
#include <hip/hip_runtime.h>
#include <hip/hip_bf16.h>

typedef unsigned short u16;

#define Bb  128
#define Ss  200
#define Tt  199   // S-1
#define Dd  128
#define Kk  4
#define NQq 10000
#define NCc 500
#define CHK 16    // scan chunk (steps staged per refill)
#define NCH 13    // ceil(199/16)

__device__ inline float bf2f(u16 u) {
    union { unsigned int i; float f; } x;
    x.i = ((unsigned int)u) << 16;
    return x.f;
}

// mode m: 1 = buffers hold fp32, 0 = buffers hold bf16
__device__ inline float ldf(const void* p, int i, int m) {
    if (m) return ((const float*)p)[i];
    return bf2f(((const u16*)p)[i]);
}

__device__ inline void stf(void* p, int i, int m, float v) {
    if (m) ((float*)p)[i] = v;
    else ((__hip_bfloat16*)p)[i] = __float2bfloat16(v);
}

__device__ inline int clampi(int v, int lo, int hi) {
    return v < lo ? lo : (v > hi ? hi : v);
}

__device__ inline float wave_red(float v) {
#pragma unroll
    for (int m = 32; m >= 1; m >>= 1) v += __shfl_xor(v, m);
    return v;
}

__device__ inline float4 f4add(float4 a, float4 b) {
    return make_float4(a.x + b.x, a.y + b.y, a.z + b.z, a.w + b.w);
}
__device__ inline float4 f4fma(float s, float4 a, float4 b) {
    return make_float4(fmaf(s, a.x, b.x), fmaf(s, a.y, b.y),
                       fmaf(s, a.z, b.z), fmaf(s, a.w, b.w));
}

// per-block inline dtype detection: scan first 256 u16 of Eq as bf16.
// fp32 data reinterpreted as bf16 shows huge/NaN values w.p. 1-1e-31.
__device__ inline int detect_mode(const void* Eq) {
    const u16* q = (const u16*)Eq;
    const int l = threadIdx.x & 63;
    float mx = 0.f;
#pragma unroll
    for (int k = 0; k < 4; ++k) {
        float a = fabsf(bf2f(q[l * 4 + k]));
        if (!(a == a)) a = 3.0e38f;
        mx = fmaxf(mx, a);
    }
#pragma unroll
    for (int s = 32; s >= 1; s >>= 1) mx = fmaxf(mx, __shfl_xor(mx, s));
    return (mx > 1.0e6f) ? 1 : 0;
}

// ---------------- K1: prep — cnorm + folded weights + small-table products -
// bi 0..499: cnorm | 500..627: BabT | 628..755: BfgT | 756: vA | 757: vF
// 758..857: PA_ut | 858..869: PA_ha | 870..969: PF_it
__global__ __launch_bounds__(128) void k_prep(
    const void* Eq, const void* Wf, const void* Wa, const void* Wg,
    const void* bfu, const void* ba, const void* bg,
    const void* Eut, const void* Eha, const void* Eit, const void* Ec,
    float* cnorm, float* BabT, float* BfgT,
    float* vA0, float* vA1, float* vF0, float* vF1,
    float* PA_ut, float* PA_ha, float* PF_it) {
    const int m = detect_mode(Eq);
    const int bi = blockIdx.x, tid = threadIdx.x;
    __shared__ float cs2s[128];
    __shared__ float tmp[2];
    if (bi < 500) {
        const int c = bi;
        float v = ldf(Ec, c * 128 + tid, m);
        float s = wave_red(v * v);
        if ((tid & 63) == 0) tmp[tid >> 6] = s;
        __syncthreads();
        if (tid == 0) cnorm[c] = fmaxf(sqrtf(tmp[0] + tmp[1]), 1e-8f);
    } else if (bi < 628) {
        const int r = bi - 500;
        float acc = 0.f;
        for (int j = 0; j < 128; ++j)
            acc += ldf(Wf, r * 128 + j, m) * ldf(Wa, j * 128 + tid, m);
        BabT[r * 128 + tid] = acc;
    } else if (bi < 756) {
        const int r = bi - 628;
        float acc = 0.f;
        for (int j = 0; j < 128; ++j)
            acc += ldf(Wf, r * 128 + j, m) * ldf(Wg, (256 + j) * 128 + tid, m);
        BfgT[r * 128 + tid] = acc;
    } else if (bi == 756) {
        float s = 0.f;
        for (int r = 0; r < 128; ++r) s += ldf(Wf, (128 + r) * 128 + tid, m);
        cs2s[tid] = s;
        __syncthreads();
        float a0 = 0.f, a1 = 0.f;
        for (int j = 0; j < 128; ++j) {
            float wv = ldf(Wa, j * 128 + tid, m);
            a0 += ldf(bfu, j, m) * wv;
            a1 += cs2s[j] * wv;
        }
        vA0[tid] = a0 + ldf(ba, tid, m);
        vA1[tid] = a1;
    } else if (bi == 757) {
        float s = 0.f;
        for (int r = 0; r < 128; ++r) s += ldf(Wf, (128 + r) * 128 + tid, m);
        cs2s[tid] = s;
        __syncthreads();
        float a0 = 0.f, a1 = 0.f;
        for (int j = 0; j < 128; ++j) {
            float wv = ldf(Wg, (256 + j) * 128 + tid, m);
            a0 += ldf(bfu, j, m) * wv;
            a1 += cs2s[j] * wv;
        }
        vF0[tid] = a0 + ldf(bg, tid, m);
        vF1[tid] = a1;
    } else if (bi < 858) {
        const int r = bi - 758;  // PA_ut
        float acc = 0.f;
        for (int j = 0; j < 128; ++j)
            acc += ldf(Eut, r * 128 + j, m) * ldf(Wa, (128 + j) * 128 + tid, m);
        PA_ut[r * 128 + tid] = acc;
    } else if (bi < 870) {
        const int r = bi - 858;  // PA_ha
        float acc = 0.f;
        for (int j = 0; j < 128; ++j)
            acc += ldf(Eha, r * 128 + j, m) * ldf(Wa, (256 + j) * 128 + tid, m);
        PA_ha[r * 128 + tid] = acc;
    } else {
        const int r = bi - 870;  // PF_it
        float acc = 0.f;
        for (int j = 0; j < 128; ++j)
            acc += ldf(Eit, r * 128 + j, m) * ldf(Wg, (128 + j) * 128 + tid, m);
        PF_it[r * 128 + tid] = acc;
    }
}

// ---------------- K2: mid — per-question GEMM (bi<313) + p2q (bi>=313) -----
__global__ __launch_bounds__(256) void k_mid(
    const void* Eq, const void* Eqd, const void* Ec,
    const int* q2c, const int* q2cm,
    const float* BabT, const float* BfgT, const float* cnorm,
    float* PA_q, float* PF_q, float* qdm, float* qd10) {
    const int m = detect_mode(Eq);
    const int tid = threadIdx.x;
    const int bi = blockIdx.x;
    if (bi < 313) {
        __shared__ float At[32][36];
        __shared__ float Bt0[32][128];
        __shared__ float Bt1[32][128];
        const int r0 = bi * 32;
        float acc0[2][8], acc1[2][8];
#pragma unroll
        for (int j = 0; j < 2; ++j)
#pragma unroll
            for (int i = 0; i < 8; ++i) { acc0[j][i] = 0.f; acc1[j][i] = 0.f; }
        const int tx = tid & 15, ty = tid >> 4;
        for (int ks = 0; ks < 4; ++ks) {
            {   // A tile: 32 rows x 32 k from Eq; 4 elements/thread
                const int row = tid >> 3, seg = tid & 7;
                const int q = clampi(r0 + row, 0, NQq - 1);
                const int ei = q * 128 + ks * 32 + seg * 4;
                float* dst = &At[row][seg * 4];
                if (m) {
                    float4 v = *(const float4*)((const float*)Eq + ei);
                    dst[0] = v.x; dst[1] = v.y; dst[2] = v.z; dst[3] = v.w;
                } else {
                    uint2 v = *(const uint2*)((const u16*)Eq + ei);
                    dst[0] = bf2f((u16)(v.x & 0xffff)); dst[1] = bf2f((u16)(v.x >> 16));
                    dst[2] = bf2f((u16)(v.y & 0xffff)); dst[3] = bf2f((u16)(v.y >> 16));
                }
            }
            {   // B tiles
                const float4* s0 = (const float4*)(BabT + ks * 32 * 128);
                const float4* s1 = (const float4*)(BfgT + ks * 32 * 128);
                float4* d0 = (float4*)&Bt0[0][0];
                float4* d1 = (float4*)&Bt1[0][0];
#pragma unroll
                for (int k = 0; k < 4; ++k) {
                    d0[tid + k * 256] = s0[tid + k * 256];
                    d1[tid + k * 256] = s1[tid + k * 256];
                }
            }
            __syncthreads();
#pragma unroll
            for (int kk = 0; kk < 32; kk += 4) {
                float a_[2][4];
                *(float4*)&a_[0][0] = *(const float4*)&At[ty * 2 + 0][kk];
                *(float4*)&a_[1][0] = *(const float4*)&At[ty * 2 + 1][kk];
#pragma unroll
                for (int q = 0; q < 4; ++q) {
                    float4 b0 = *(const float4*)&Bt0[kk + q][tx * 8];
                    float4 b1 = *(const float4*)&Bt0[kk + q][tx * 8 + 4];
                    float4 c0 = *(const float4*)&Bt1[kk + q][tx * 8];
                    float4 c1 = *(const float4*)&Bt1[kk + q][tx * 8 + 4];
#pragma unroll
                    for (int j = 0; j < 2; ++j) {
                        const float av = a_[j][q];
                        acc0[j][0] += av * b0.x; acc0[j][1] += av * b0.y;
                        acc0[j][2] += av * b0.z; acc0[j][3] += av * b0.w;
                        acc0[j][4] += av * b1.x; acc0[j][5] += av * b1.y;
                        acc0[j][6] += av * b1.z; acc0[j][7] += av * b1.w;
                        acc1[j][0] += av * c0.x; acc1[j][1] += av * c0.y;
                        acc1[j][2] += av * c0.z; acc1[j][3] += av * c0.w;
                        acc1[j][4] += av * c1.x; acc1[j][5] += av * c1.y;
                        acc1[j][6] += av * c1.z; acc1[j][7] += av * c1.w;
                    }
                }
            }
            __syncthreads();
        }
#pragma unroll
        for (int j = 0; j < 2; ++j) {
            const int q = r0 + ty * 2 + j;
            if (q < NQq) {
                float* oa = PA_q + q * 128 + tx * 8;
                float* of = PF_q + q * 128 + tx * 8;
#pragma unroll
                for (int i = 0; i < 8; ++i) { oa[i] = acc0[j][i]; of[i] = acc1[j][i]; }
            }
        }
    } else {
        // p2q: per-question qdm + qd10
        const int wv = tid >> 6, lane = tid & 63;
        const int q = (bi - 313) * 4 + wv;  // 2500*4 == 10000
        const float qa = ldf(Eq, q * 128 + lane, m);
        const float qb = ldf(Eq, q * 128 + 64 + lane, m);
        const float nqc = fmaxf(sqrtf(wave_red(qa * qa + qb * qb)), 1e-8f);
        const int4 cc = ((const int4*)q2c)[q];
        const int4 mm = ((const int4*)q2cm)[q];
        const int cks[4] = {clampi(cc.x, 0, NCc - 1), clampi(cc.y, 0, NCc - 1),
                            clampi(cc.z, 0, NCc - 1), clampi(cc.w, 0, NCc - 1)};
        const int ms[4]  = {mm.x, mm.y, mm.z, mm.w};
        float qs = 0.f;
#pragma unroll
        for (int k = 0; k < 4; ++k) {
            const int ck = cks[k];
            float dot = wave_red(qa * ldf(Ec, ck * 128 + lane, m) +
                                 qb * ldf(Ec, ck * 128 + 64 + lane, m));
            qs += (float)ms[k] * (0.5f * dot / (nqc * cnorm[ck]) + 0.5f);
        }
        if (lane == 0) {
            qdm[q] = qs;
            qd10[q] = 10.f / (1.f + __expf(-ldf(Eqd, q, m)));
        }
    }
}

// ---------------- K3: scan — TWO interleaved chains per block --------------
// b = 2*blockIdx + ch. Chains are independent serial recurrences sharing W;
// interleaving hides each chain's LDS/barrier latency behind the other's
// VALU phase. One barrier per 2 chain-steps (part parity double-buffered).
// lp broadcast via v_readlane from own wave's lc regs (no LDS pipe).
__global__ __launch_bounds__(256) void p4_scan(
    const int* q_seq, const int* ut_seq, const int* ha_seq, const int* it_seq,
    const int* c_seq,
    const void* Eq, const void* Wg, const void* L0,
    const float* PA_q, const float* PA_ut, const float* PA_ha,
    const float* PF_q, const float* PF_it,
    const float* vA0, const float* vA1, const float* vF0, const float* vF1,
    float* lc_seq) {
    const int m = detect_mode(Eq);
    const int b0 = blockIdx.x * 2;
    const int tid = threadIdx.x;
    const int wv = tid >> 6, l = tid & 63;
    const int d0 = 2 * l;              // partial-column pair (phase A)
    const int ib = wv << 5;            // wave's i-range / state base
    const int dd = ib + (l & 31);      // owned state index (lanes<32)

    __shared__ float part[2][2][4][128];   // [parity][chain][wave][col]
    __shared__ float st_ab[2][CHK * 128];  // [chain][...]
    __shared__ float st_pf[2][CHK * 128];

    float wA[32], wB[32];
#pragma unroll
    for (int k = 0; k < 32; ++k) {
        wA[k] = ldf(Wg, (ib + k) * 128 + d0, m);
        wB[k] = ldf(Wg, (ib + k) * 128 + d0 + 1, m);
    }
    float lc[2];
#pragma unroll
    for (int ch = 0; ch < 2; ++ch)
        lc[ch] = (l < 32) ? ldf(L0, (b0 + ch) * 128 + dd, m) : 0.f;

    // staging role: thread -> (row srow in chunk, 8-float segment seg)
    const int srow = tid >> 4, seg = tid & 15;
    const int off8 = seg * 8;
    const float4 A0a = *(const float4*)(vA0 + off8), A0b = *(const float4*)(vA0 + off8 + 4);
    const float4 A1a = *(const float4*)(vA1 + off8), A1b = *(const float4*)(vA1 + off8 + 4);
    const float4 F0a = *(const float4*)(vF0 + off8), F0b = *(const float4*)(vF0 + off8 + 4);
    const float4 F1a = *(const float4*)(vF1 + off8), F1b = *(const float4*)(vF1 + off8 + 4);

    float4 qa0[2], qa1[2], ua0[2], ua1[2], ga0[2], ga1[2];
    float4 qf0[2], qf1[2], if0[2], if1[2];
    float cf[2];
#define LOAD_CHUNK(C, CH)                                                      \
    {                                                                          \
        int tt = (C) * CHK + srow; if (tt > Tt - 1) tt = Tt - 1;               \
        const int base = (b0 + (CH)) * Ss + tt;                                \
        const int qt = clampi(q_seq[base], 0, NQq - 1);                        \
        const int ut = clampi(ut_seq[base], 0, 99);                            \
        const int ha = clampi(ha_seq[base], 0, 11);                            \
        const int it = clampi(it_seq[base], 0, 99);                            \
        cf[CH] = (float)c_seq[base];                                           \
        const float* pq = PA_q + qt * 128 + off8;                              \
        qa0[CH] = *(const float4*)pq; qa1[CH] = *(const float4*)(pq + 4);      \
        const float* pu = PA_ut + ut * 128 + off8;                             \
        ua0[CH] = *(const float4*)pu; ua1[CH] = *(const float4*)(pu + 4);      \
        const float* ph = PA_ha + ha * 128 + off8;                             \
        ga0[CH] = *(const float4*)ph; ga1[CH] = *(const float4*)(ph + 4);      \
        const float* pf = PF_q + qt * 128 + off8;                              \
        qf0[CH] = *(const float4*)pf; qf1[CH] = *(const float4*)(pf + 4);      \
        const float* pi = PF_it + it * 128 + off8;                             \
        if0[CH] = *(const float4*)pi; if1[CH] = *(const float4*)(pi + 4);      \
    }

    LOAD_CHUNK(0, 0)
    LOAD_CHUNK(0, 1)
    float lcbuf[2][CHK];

    for (int c = 0; c < NCH; ++c) {
        __syncthreads();   // prior chunk's st readers done
#pragma unroll
        for (int ch = 0; ch < 2; ++ch) {   // publish staged chunk c
            float4 ab0 = f4fma(cf[ch], A1a,
                               f4add(f4add(qa0[ch], ua0[ch]), f4add(ga0[ch], A0a)));
            float4 ab1 = f4fma(cf[ch], A1b,
                               f4add(f4add(qa1[ch], ua1[ch]), f4add(ga1[ch], A0b)));
            float4 pf0 = f4fma(cf[ch], F1a, f4add(qf0[ch], f4add(if0[ch], F0a)));
            float4 pf1 = f4fma(cf[ch], F1b, f4add(qf1[ch], f4add(if1[ch], F0b)));
            float4* sa = (float4*)(st_ab[ch] + srow * 128 + off8);
            sa[0] = ab0; sa[1] = ab1;
            float4* sp = (float4*)(st_pf[ch] + srow * 128 + off8);
            sp[0] = pf0; sp[1] = pf1;
        }
        if (c + 1 < NCH) { LOAD_CHUNK(c + 1, 0) LOAD_CHUNK(c + 1, 1) }
        __syncthreads();   // st visible

        int par = 0;
#pragma unroll
        for (int s = 0; s < CHK; ++s) {
            // phase A, both chains: readlane matvec, write partials
#pragma unroll
            for (int ch = 0; ch < 2; ++ch) {
                float pa = 0.f, pb = 0.f;
#pragma unroll
                for (int k = 0; k < 32; ++k) {
                    const float u = __uint_as_float(
                        __builtin_amdgcn_readlane(__float_as_uint(lc[ch]), k));
                    pa = fmaf(u, wA[k], pa);
                    pb = fmaf(u, wB[k], pb);
                }
                *(float2*)&part[par][ch][wv][d0] = make_float2(pa, pb);
            }
            __syncthreads();   // the ONLY barrier per 2 chain-steps
            // phase B, both chains: reduce + recurrence (lanes < 32)
            if (l < 32) {
#pragma unroll
                for (int ch = 0; ch < 2; ++ch) {
                    const float fs = part[par][ch][0][dd] + part[par][ch][1][dd]
                                   + part[par][ch][2][dd] + part[par][ch][3][dd];
                    const float ab = st_ab[ch][(s << 7) + dd];
                    const float pf = st_pf[ch][(s << 7) + dd];
                    const float fg = 1.f / (1.f + __expf(-(fs + pf)));
                    lc[ch] = lc[ch] * fg + ab;
                    lcbuf[ch][s] = lc[ch];
                }
            }
            par ^= 1;
        }
        // flush lc history for chunk c
        if (l < 32) {
#pragma unroll
            for (int s = 0; s < CHK; ++s) {
                const int t = c * CHK + s;
                if (t < Tt) {
                    lc_seq[((long)t * 128 + b0) * 128 + dd]     = lcbuf[0][s];
                    lc_seq[((long)t * 128 + b0 + 1) * 128 + dd] = lcbuf[1][s];
                }
            }
        }
    }
#undef LOAD_CHUNK
}

// ---------------- K4: parallel cosine/logit epilogue (one wave per row) ----
__global__ __launch_bounds__(256) void p5_out(
    const int* q_seq, const int* q2c, const int* q2cm,
    const float* lc_seq, const float* qdm, const float* qd10,
    const float* cnorm, const void* Eq, const void* Ec, void* out) {
    const int m = detect_mode(Eq);
    const int wv = threadIdx.x >> 6, lane = threadIdx.x & 63;
    const int r = blockIdx.x * 4 + wv;  // 6368*4 == 25472 == Tt*Bb
    const int t = r >> 7, b = r & 127;
    const int qt  = clampi(q_seq[b * Ss + t], 0, NQq - 1);
    const int qt1 = clampi(q_seq[b * Ss + t + 1], 0, NQq - 1);
    const int4 mm = ((const int4*)q2cm)[qt];
    int4 ci = ((const int4*)q2c)[qt1];
    const int c0 = clampi(ci.x, 0, NCc - 1), c1 = clampi(ci.y, 0, NCc - 1);
    const int c2 = clampi(ci.z, 0, NCc - 1), c3 = clampi(ci.w, 0, NCc - 1);
    const float la = lc_seq[(long)r * 128 + lane];
    const float lb = lc_seq[(long)r * 128 + 64 + lane];
    float nl = la * la + lb * lb;
    float d0 = la * ldf(Ec, c0 * 128 + lane, m) + lb * ldf(Ec, c0 * 128 + 64 + lane, m);
    float d1 = la * ldf(Ec, c1 * 128 + lane, m) + lb * ldf(Ec, c1 * 128 + 64 + lane, m);
    float d2 = la * ldf(Ec, c2 * 128 + lane, m) + lb * ldf(Ec, c2 * 128 + 64 + lane, m);
    float d3 = la * ldf(Ec, c3 * 128 + lane, m) + lb * ldf(Ec, c3 * 128 + 64 + lane, m);
#pragma unroll
    for (int s = 32; s >= 1; s >>= 1) {
        nl += __shfl_xor(nl, s);
        d0 += __shfl_xor(d0, s); d1 += __shfl_xor(d1, s);
        d2 += __shfl_xor(d2, s); d3 += __shfl_xor(d3, s);
    }
    if (lane == 0) {
        const float inl = 1.f / fmaxf(sqrtf(nl), 1e-8f);
        const float accv = (float)mm.x * (0.5f * d0 * inl / cnorm[c0] + 0.5f)
                         + (float)mm.y * (0.5f * d1 * inl / cnorm[c1] + 0.5f)
                         + (float)mm.z * (0.5f * d2 * inl / cnorm[c2] + 0.5f)
                         + (float)mm.w * (0.5f * d3 * inl / cnorm[c3] + 0.5f);
        const float logit = qd10[qt1] * (accv - qdm[qt]);
        stf(out, b * Ss + t, m, 1.f / (1.f + __expf(-logit)));
        if (t == 0) stf(out, b * Ss + 199, m, 0.f);
    }
}

extern "C" void kernel_launch(void* const* d_in, const int* in_sizes, int n_in,
                              void* d_out, int out_size, void* d_ws, size_t ws_size,
                              hipStream_t stream) {
    (void)in_sizes; (void)n_in; (void)out_size; (void)ws_size;
    const int* q_seq  = (const int*)d_in[0];
    const int* ha_seq = (const int*)d_in[1];
    const int* c_seq  = (const int*)d_in[2];
    const int* it_seq = (const int*)d_in[3];
    const int* ut_seq = (const int*)d_in[4];
    const int* q2c    = (const int*)d_in[5];
    const int* q2cm   = (const int*)d_in[6];
    const void* Eq   = d_in[7];
    const void* Eqd  = d_in[8];
    const void* Ec   = d_in[9];
    const void* Eit  = d_in[10];
    const void* Eut  = d_in[11];
    const void* Eha  = d_in[12];
    const void* Wf   = d_in[13];
    const void* bfu  = d_in[14];
    const void* Wa   = d_in[15];
    const void* ba   = d_in[16];
    const void* Wg   = d_in[17];
    const void* bg   = d_in[18];
    const void* L0   = d_in[19];

    // workspace layout (floats) — ~23.5 MB
    float* cnorm = (float*)d_ws;                // 512 (500 used)
    float* vA0   = cnorm + 512;                 // 128 x4
    float* vA1   = vA0 + 128;
    float* vF0   = vA1 + 128;
    float* vF1   = vF0 + 128;
    float* BabT  = vF1 + 128;                   // 16384
    float* BfgT  = BabT + 16384;                // 16384
    float* PA_ut = BfgT + 16384;                // 12800
    float* PA_ha = PA_ut + 12800;               // 1536
    float* PF_it = PA_ha + 1536;                // 12800
    float* qdm   = PF_it + 12800;               // 10016
    float* qd10  = qdm + 10016;                 // 10016
    float* PA_q  = qd10 + 10016;                // 1,280,000
    float* PF_q  = PA_q + 1280000;              // 1,280,000
    float* lc_seq= PF_q + 1280000;              // 3,260,416

    hipLaunchKernelGGL(k_prep, dim3(970), dim3(128), 0, stream,
                       Eq, Wf, Wa, Wg, bfu, ba, bg, Eut, Eha, Eit, Ec,
                       cnorm, BabT, BfgT, vA0, vA1, vF0, vF1, PA_ut, PA_ha, PF_it);
    hipLaunchKernelGGL(k_mid, dim3(2813), dim3(256), 0, stream,
                       Eq, Eqd, Ec, q2c, q2cm, BabT, BfgT, cnorm,
                       PA_q, PF_q, qdm, qd10);
    hipLaunchKernelGGL(p4_scan, dim3(Bb / 2), dim3(256), 0, stream,
                       q_seq, ut_seq, ha_seq, it_seq, c_seq, Eq, Wg, L0,
                       PA_q, PA_ut, PA_ha, PF_q, PF_it,
                       vA0, vA1, vF0, vF1, lc_seq);
    hipLaunchKernelGGL(p5_out, dim3(Tt * Bb / 4), dim3(256), 0, stream,
                       q_seq, q2c, q2cm, lc_seq, qdm, qd10, cnorm, Eq, Ec, d_out);
}